// Round 1
// baseline (1545.109 us; speedup 1.0000x reference)
//
#include <hip/hip_runtime.h>

typedef unsigned short ushort_t;
typedef unsigned int uint_t;
typedef __attribute__((ext_vector_type(8))) short s8bf;   // 8 x bf16 MFMA fragment
typedef __attribute__((ext_vector_type(4))) float f32x4;  // MFMA accumulator

#define N2 127

__device__ inline float bf_lo(uint_t v){ return __uint_as_float(v << 16); }
__device__ inline float bf_hi(uint_t v){ return __uint_as_float(v & 0xffff0000u); }
__device__ inline ushort_t f2bf(float f){
  uint_t u = __float_as_uint(f);
  uint_t r = ((u >> 16) & 1u) + 0x7fffu;  // RNE
  return (ushort_t)((u + r) >> 16);
}
__device__ inline float bf2f(ushort_t h){ return __uint_as_float(((uint_t)h) << 16); }
__device__ inline float frcp(float x){ return __builtin_amdgcn_rcpf(x); }
__device__ inline float sigm(float x){ return frcp(1.f + __expf(-x)); }
__device__ inline float tanhf_(float x){
  float xc = fminf(fmaxf(x, -15.f), 15.f);
  float e = __expf(2.f * xc);
  return (e - 1.f) * frcp(e + 1.f);
}
__device__ inline void unpack8(uint4 u, float* x){
  x[0]=bf_lo(u.x); x[1]=bf_hi(u.x); x[2]=bf_lo(u.y); x[3]=bf_hi(u.y);
  x[4]=bf_lo(u.z); x[5]=bf_hi(u.z); x[6]=bf_lo(u.w); x[7]=bf_hi(u.w);
}
__device__ inline void unpack8_add(uint4 u, float* x){
  x[0]+=bf_lo(u.x); x[1]+=bf_hi(u.x); x[2]+=bf_lo(u.y); x[3]+=bf_hi(u.y);
  x[4]+=bf_lo(u.z); x[5]+=bf_hi(u.z); x[6]+=bf_lo(u.w); x[7]+=bf_hi(u.w);
}
__device__ inline f32x4 zero4(){ f32x4 v; v[0]=0.f; v[1]=0.f; v[2]=0.f; v[3]=0.f; return v; }

// ---------------------------------------------------------------------------
// Pack weights: z-weights [wis;wss0;wss1] (256x256) and woc (64x128) into
// MFMA B-fragment order (B[k][n], lane = quad*?: k=kk*32+quad*8+e, n=ct*16+l16),
// fused z bias, transposed head weights, compacted conv taps.
// ---------------------------------------------------------------------------
__global__ void pack_kernel(const float* __restrict__ w_is, const float* __restrict__ w_ss,
                            const float* __restrict__ b_is, const float* __restrict__ b_ss,
                            const float* __restrict__ w_oc, const float* __restrict__ w1,
                            const float* __restrict__ w2, const float* __restrict__ wh,
                            const float* __restrict__ ck,
                            ushort_t* __restrict__ zWp, ushort_t* __restrict__ wocp,
                            float* __restrict__ zbias, float* __restrict__ w1T,
                            float* __restrict__ w2T, float* __restrict__ whT,
                            float* __restrict__ kw)
{
  int idx = blockIdx.x * 256 + threadIdx.x;
  if (idx < 262144){                       // zW fragments: 4 (l,d) x 65536
    int ld = idx >> 16; int r = idx & 65535;
    int e = r & 7, lane = (r >> 3) & 63, ctg = (r >> 9) & 15, kk = r >> 13;
    int k = kk*32 + ((lane >> 4) & 3)*8 + e;
    int n = ctg*16 + (lane & 15);
    float v;
    if (k < 128) v = w_is[((size_t)ld*128 + k)*256 + n];
    else { int s = (k - 128) >> 6, kr = (k - 128) & 63;
           v = w_ss[(((size_t)ld*2 + s)*64 + kr)*256 + n]; }
    zWp[idx] = f2bf(v);
  } else if (idx < 262144 + 32768){        // woc fragments: 4 x 8192
    int r0 = idx - 262144;
    int ld = r0 >> 13; int r = r0 & 8191;
    int e = r & 7, lane = (r >> 3) & 63, ctg = (r >> 9) & 7, kk = (r >> 12) & 1;
    int k = kk*32 + ((lane >> 4) & 3)*8 + e;
    int n = ctg*16 + (lane & 15);
    wocp[r0] = f2bf(w_oc[((size_t)ld*64 + k)*128 + n]);
  } else if (idx < 262144 + 32768 + 1024){ // fused z bias
    int r = idx - (262144 + 32768);
    zbias[r] = b_is[r] + b_ss[r];
  } else if (idx < 262144+32768+1024+4096){        // w_out1^T (32,128)
    int r = idx - (262144+32768+1024);
    int c = r >> 7, k = r & 127;
    w1T[r] = w1[k*32 + c];
  } else if (idx < 262144+32768+1024+4096+1024){   // w_out2^T (32,32)
    int r = idx - (262144+32768+1024+4096);
    int c = r >> 5, k = r & 31;
    w2T[r] = w2[k*32 + c];
  } else if (idx < 262144+32768+1024+4096+1024+8192){ // w_head^T (256,32)
    int r = idx - (262144+32768+1024+4096+1024);
    int o = r >> 5, k = r & 31;
    whT[r] = wh[k*256 + o];
  } else {                                 // 24 live conv taps x 128 ch
    int r = idx - (262144+32768+1024+4096+1024+8192);
    int tau = r >> 7, ch = r & 127;
    int di, dj;
    if (tau < 21){ di = tau/7 - 3; dj = tau%7 - 3; } else { di = 0; dj = tau - 24; }
    kw[r] = ck[((di+3)*7 + (dj+3))*128 + ch];
  }
}

// ---------------------------------------------------------------------------
// Masked 7x7 conv applied directly on the implicit skewed image.
// skew(b,i,j') = im[b,i,j'-i] if 0<=j'-i<64 else 0. Output bf16 (B,64,127,128).
// ---------------------------------------------------------------------------
__global__ __launch_bounds__(256) void conv_kernel(const float* __restrict__ im,
                const float* __restrict__ cb, const float* __restrict__ kw,
                ushort_t* __restrict__ out)
{
  int tid = threadIdx.x;
  int p = blockIdx.x*2 + (tid >> 7);       // (b,i,j) position
  int ch = tid & 127;
  int b = p / (64*N2); int rem = p - b*(64*N2);
  int i = rem / N2; int j = rem - i*N2;
  int base = j - i;
  float acc = cb[ch];
#pragma unroll
  for (int tau = 0; tau < 24; tau++){
    int di = (tau < 21) ? (tau/7 - 3) : 0;
    int dj = (tau < 21) ? (tau%7 - 3) : (tau - 24);
    int ii = i + di;
    int jx = base + dj - di;               // column in the un-skewed image
    if (ii >= 0 && jx >= 0 && jx < 64)
      acc += im[(b*64 + ii)*64 + jx] * kw[tau*128 + ch];
  }
  out[(size_t)p*128 + ch] = f2bf(acc);
}

// ---------------------------------------------------------------------------
// Diagonal LSTM layer: one block per (batch b, direction d); 127 sequential
// steps. Weights preloaded in registers; gates + c entirely in-register via
// strided col-tile wave assignment; A = [xn | hprev | h] in LDS (bf16).
// ---------------------------------------------------------------------------
__global__ __launch_bounds__(256, 1) void diag_kernel(
    const ushort_t* __restrict__ inL, const ushort_t* __restrict__ inR,
    ushort_t* __restrict__ outL, ushort_t* __restrict__ outR,
    const ushort_t* __restrict__ zWp, const ushort_t* __restrict__ wocp,
    const float* __restrict__ zbias, const float* __restrict__ ln_s,
    const float* __restrict__ ln_b, const float* __restrict__ b_oc,
    const float* __restrict__ h0, int layer)
{
  __shared__ ushort_t A[64][264];          // [xn(0:128) | hprev(128:192) | h(192:256)], +8 pad
  __shared__ float lns_l[128], lnb_l[128];

  const int tid = threadIdx.x;
  const int b = blockIdx.x & 15;
  const int d = blockIdx.x >> 4;
  const int ld = layer*2 + d;
  ushort_t* outp = d ? outR : outL;

  const ushort_t* zW  = zWp  + (size_t)ld*65536;
  const ushort_t* wocW= wocp + (size_t)ld*8192;
  const float* zb  = zbias + ld*256;
  const float* h0p = h0 + ld*64;

  const int w = tid >> 6;
  const int lane = tid & 63;
  const int quad = lane >> 4;
  const int l16 = lane & 15;
  const int cg = w*16 + l16;               // column within each 64-wide gate

  // Preload all B fragments into registers (wave w owns col tiles {w, w+4, w+8, w+12}).
  s8bf bz[8][4];
#pragma unroll
  for (int kk = 0; kk < 8; kk++)
#pragma unroll
    for (int ct = 0; ct < 4; ct++)
      bz[kk][ct] = *(const s8bf*)(zW + (size_t)(((kk*16 + (w + 4*ct))*64 + lane)*8));
  s8bf bw[2][2];                           // woc: wave w owns cols [32w, 32w+32)
#pragma unroll
  for (int kk = 0; kk < 2; kk++)
#pragma unroll
    for (int jt = 0; jt < 2; jt++)
      bw[kk][jt] = *(const s8bf*)(wocW + (size_t)(((kk*8 + (2*w + jt))*64 + lane)*8));

  const float zbF = zb[cg], zbI = zb[64+cg], zbO = zb[128+cg], zbG = zb[192+cg];
  const float bocv0 = b_oc[ld*128 + 32*w + l16];
  const float bocv1 = b_oc[ld*128 + 32*w + 16 + l16];

  float c_reg[16];                         // LSTM cell state, never leaves registers
#pragma unroll
  for (int k = 0; k < 16; k++) c_reg[k] = 0.f;

  if (tid < 128){ lns_l[tid] = ln_s[ld*128 + tid]; lnb_l[tid] = ln_b[ld*128 + tid]; }
  { // init h slots: carry h_{-1} = h0 (broadcast); hprev row 0 = 0 forever
    int row = tid >> 2, q = tid & 3;
#pragma unroll
    for (int k = 0; k < 16; k++){
      int c = q*16 + k;
      ushort_t hb = f2bf(h0p[c]);
      A[row][192 + c] = hb;
      A[row][128 + c] = (row == 0) ? (ushort_t)0 : hb;
    }
  }
  __syncthreads();

  const int lrow = tid >> 2, lq = tid & 3;
  const bool hasR = (inR != nullptr) && (lrow > 0);
  const size_t rowL = (size_t)(b*64 + lrow)*N2;
  const size_t rowR = hasR ? (size_t)(b*64 + lrow - 1)*N2 : 0;

  uint4 xL0,xL1,xL2,xL3, xR0,xR1,xR2,xR3;
  xR0=xR1=xR2=xR3=make_uint4(0,0,0,0);
  { // prefetch t=0
    int jp = d ? 126 : 0;
    const uint4* pL = (const uint4*)(inL + (rowL + jp)*128 + lq*32);
    xL0=pL[0]; xL1=pL[1]; xL2=pL[2]; xL3=pL[3];
    if (hasR){ const uint4* pR = (const uint4*)(inR + (rowR + jp)*128 + lq*32);
               xR0=pR[0]; xR1=pR[1]; xR2=pR[2]; xR3=pR[3]; }
  }

#pragma unroll 1
  for (int t = 0; t < 127; t++){
    const int j = d ? (126 - t) : t;
    // ---- phase 1: combine inputs + LayerNorm -> A[:,0:128] bf16 ----
    float x[32];
    unpack8(xL0, x); unpack8(xL1, x+8); unpack8(xL2, x+16); unpack8(xL3, x+24);
    if (hasR){ unpack8_add(xR0, x); unpack8_add(xR1, x+8);
               unpack8_add(xR2, x+16); unpack8_add(xR3, x+24); }
    float s0=0.f,s1=0.f,s2=0.f,s3=0.f, q0=0.f,q1=0.f,q2=0.f,q3=0.f;
#pragma unroll
    for (int k = 0; k < 32; k += 4){
      s0 += x[k];   q0 += x[k]*x[k];
      s1 += x[k+1]; q1 += x[k+1]*x[k+1];
      s2 += x[k+2]; q2 += x[k+2]*x[k+2];
      s3 += x[k+3]; q3 += x[k+3]*x[k+3];
    }
    float s = (s0+s1)+(s2+s3), ss = (q0+q1)+(q2+q3);
    s  += __shfl_xor(s, 1);  ss += __shfl_xor(ss, 1);
    s  += __shfl_xor(s, 2);  ss += __shfl_xor(ss, 2);
    float mu = s * 0.0078125f;
    float var = ss * 0.0078125f - mu*mu;
    float rstd = rsqrtf(var + 1e-6f);
#pragma unroll
    for (int k = 0; k < 32; k++){
      int c = lq*32 + k;
      float xn = (x[k] - mu)*rstd*lns_l[c] + lnb_l[c];
      A[lrow][c] = f2bf(xn);
    }
    __syncthreads(); // B1: xn ready

    // prefetch next step's input (latency overlapped with MFMA phase)
    if (t < 126){
      int jp = d ? (126 - (t+1)) : (t+1);
      const uint4* pL = (const uint4*)(inL + (rowL + jp)*128 + lq*32);
      xL0=pL[0]; xL1=pL[1]; xL2=pL[2]; xL3=pL[3];
      if (hasR){ const uint4* pR = (const uint4*)(inR + (rowR + jp)*128 + lq*32);
                 xR0=pR[0]; xR1=pR[1]; xR2=pR[2]; xR3=pR[3]; }
    }

    // ---- phase 2: z = [xn|hprev|h] @ [wis;wss0;wss1]  (64x256 @ 256x256) ----
    f32x4 acc[4][4];
#pragma unroll
    for (int rt = 0; rt < 4; rt++)
#pragma unroll
      for (int ct = 0; ct < 4; ct++) acc[rt][ct] = zero4();
    s8bf a_cur[4], a_nxt[4];
#pragma unroll
    for (int rt = 0; rt < 4; rt++) a_cur[rt] = *(const s8bf*)&A[rt*16 + l16][quad*8];
#pragma unroll
    for (int kk = 0; kk < 8; kk++){
      if (kk < 7){
#pragma unroll
        for (int rt = 0; rt < 4; rt++)
          a_nxt[rt] = *(const s8bf*)&A[rt*16 + l16][(kk+1)*32 + quad*8];
      }
#pragma unroll
      for (int rt = 0; rt < 4; rt++)
#pragma unroll
        for (int ct = 0; ct < 4; ct++)
          acc[rt][ct] = __builtin_amdgcn_mfma_f32_16x16x32_bf16(a_cur[rt], bz[kk][ct], acc[rt][ct], 0, 0, 0);
      if (kk < 7){
#pragma unroll
        for (int rt = 0; rt < 4; rt++) a_cur[rt] = a_nxt[rt];
      }
    }
    __syncthreads(); // B2: all waves done reading A's h columns

    // ---- phase 3: gates in-register (ct index == gate index), update c, h ----
#pragma unroll
    for (int rt = 0; rt < 4; rt++){
#pragma unroll
      for (int r = 0; r < 4; r++){
        int idx = rt*4 + r;
        float fg = sigm(acc[rt][0][r] + zbF);
        float ig = sigm(acc[rt][1][r] + zbI);
        float og = sigm(acc[rt][2][r] + zbO);
        float gg = tanhf_(acc[rt][3][r] + zbG);
        float cn = fg*c_reg[idx] + ig*gg;
        c_reg[idx] = cn;
        float hn = og * tanhf_(cn);
        int rr = rt*16 + quad*4 + r;
        ushort_t hb = f2bf(hn);
        A[rr][192 + cg] = hb;                    // h slot for next step & woc matmul
        if (rr < 63) A[rr+1][128 + cg] = hb;     // hprev slot (m-shift)
      }
    }
    __syncthreads(); // B3: new h complete

    // ---- phase 4: x_out = hn @ woc + boc + xn; store bf16 ----
    f32x4 acc2[4][2];
#pragma unroll
    for (int rt = 0; rt < 4; rt++){ acc2[rt][0] = zero4(); acc2[rt][1] = zero4(); }
#pragma unroll
    for (int kk = 0; kk < 2; kk++){
#pragma unroll
      for (int rt = 0; rt < 4; rt++){
        s8bf a2 = *(const s8bf*)&A[rt*16 + l16][192 + kk*32 + quad*8];
#pragma unroll
        for (int jt = 0; jt < 2; jt++)
          acc2[rt][jt] = __builtin_amdgcn_mfma_f32_16x16x32_bf16(a2, bw[kk][jt], acc2[rt][jt], 0, 0, 0);
      }
    }
#pragma unroll
    for (int rt = 0; rt < 4; rt++){
#pragma unroll
      for (int jt = 0; jt < 2; jt++){
        float bocv = jt ? bocv1 : bocv0;
        int col = 32*w + 16*jt + l16;
#pragma unroll
        for (int r = 0; r < 4; r++){
          int rr = rt*16 + quad*4 + r;
          float v = acc2[rt][jt][r] + bocv + bf2f(A[rr][col]); // residual = xn (bf16)
          outp[((size_t)(b*64 + rr)*N2 + j)*128 + col] = f2bf(v);
        }
      }
    }
    __syncthreads(); // B4: protect A/xn before next step's phase 1
  }
}

// ---------------------------------------------------------------------------
// Head: unskew + (128->32)->(32->32)->(32->256), fp32 vector math.
// One block per (b, i); combines left + m-shifted right of the last layer.
// ---------------------------------------------------------------------------
__global__ __launch_bounds__(256) void head_kernel(
    const ushort_t* __restrict__ L1, const ushort_t* __restrict__ R1,
    const float* __restrict__ w1T, const float* __restrict__ b1,
    const float* __restrict__ w2T, const float* __restrict__ b2,
    const float* __restrict__ whT, const float* __restrict__ bh,
    float* __restrict__ out)
{
  __shared__ float xf[64][132];
  __shared__ float v1[64][36];
  __shared__ float v2[64][36];
  int tid = threadIdx.x;
  int b = blockIdx.x >> 6, i = blockIdx.x & 63;
  {
    int jj = tid >> 2, q = tid & 3;
    size_t base = ((size_t)(b*64 + i)*N2 + (i + jj))*128 + q*32;  // unskew: j' = i + j
    const uint4* pL = (const uint4*)(L1 + base);
    float x[32];
    unpack8(pL[0], x); unpack8(pL[1], x+8); unpack8(pL[2], x+16); unpack8(pL[3], x+24);
    if (i > 0){
      size_t baseR = ((size_t)(b*64 + i - 1)*N2 + (i + jj))*128 + q*32;
      const uint4* pR = (const uint4*)(R1 + baseR);
      unpack8_add(pR[0], x); unpack8_add(pR[1], x+8); unpack8_add(pR[2], x+16); unpack8_add(pR[3], x+24);
    }
#pragma unroll
    for (int k = 0; k < 32; k++) xf[jj][q*32 + k] = x[k];
  }
  __syncthreads();
  { // v1 = x @ w1 + b1
    int c1 = tid & 31, jg = tid >> 5;
    float wr[128];
    const float4* wp = (const float4*)(w1T + c1*128);
#pragma unroll
    for (int kk = 0; kk < 32; kk++) ((float4*)wr)[kk] = wp[kk];
#pragma unroll 1
    for (int jj2 = 0; jj2 < 8; jj2++){
      int jr = jg*8 + jj2;
      float a0=0.f,a1=0.f,a2=0.f,a3=0.f;
#pragma unroll
      for (int kk = 0; kk < 32; kk++){
        float4 xv = *(const float4*)&xf[jr][kk*4];
        a0 += xv.x*wr[kk*4]; a1 += xv.y*wr[kk*4+1]; a2 += xv.z*wr[kk*4+2]; a3 += xv.w*wr[kk*4+3];
      }
      v1[jr][c1] = b1[c1] + (a0+a1)+(a2+a3);
    }
  }
  __syncthreads();
  { // v2 = v1 @ w2 + b2
    int c2 = tid & 31, jg = tid >> 5;
    float wr[32];
    const float4* wp = (const float4*)(w2T + c2*32);
#pragma unroll
    for (int kk = 0; kk < 8; kk++) ((float4*)wr)[kk] = wp[kk];
#pragma unroll 1
    for (int jj2 = 0; jj2 < 8; jj2++){
      int jr = jg*8 + jj2;
      float a0=0.f,a1=0.f,a2=0.f,a3=0.f;
#pragma unroll
      for (int kk = 0; kk < 8; kk++){
        float4 xv = *(const float4*)&v1[jr][kk*4];
        a0 += xv.x*wr[kk*4]; a1 += xv.y*wr[kk*4+1]; a2 += xv.z*wr[kk*4+2]; a3 += xv.w*wr[kk*4+3];
      }
      v2[jr][c2] = b2[c2] + (a0+a1)+(a2+a3);
    }
  }
  __syncthreads();
  { // out = v2 @ wh + bh
    int o = tid;
    float wr[32];
    const float4* wp = (const float4*)(whT + o*32);
#pragma unroll
    for (int kk = 0; kk < 8; kk++) ((float4*)wr)[kk] = wp[kk];
    float bo = bh[o];
#pragma unroll 1
    for (int jr = 0; jr < 64; jr++){
      float a0=0.f,a1=0.f,a2=0.f,a3=0.f;
#pragma unroll
      for (int kk = 0; kk < 8; kk++){
        float4 xv = *(const float4*)&v2[jr][kk*4];
        a0 += xv.x*wr[kk*4]; a1 += xv.y*wr[kk*4+1]; a2 += xv.z*wr[kk*4+2]; a3 += xv.w*wr[kk*4+3];
      }
      out[(((size_t)b*64 + i)*64 + jr)*256 + o] = bo + (a0+a1)+(a2+a3);
    }
  }
}

// ---------------------------------------------------------------------------
extern "C" void kernel_launch(void* const* d_in, const int* in_sizes, int n_in,
                              void* d_out, int out_size, void* d_ws, size_t ws_size,
                              hipStream_t stream)
{
  const float* im   = (const float*)d_in[0];
  const float* ck   = (const float*)d_in[1];
  const float* cb   = (const float*)d_in[2];
  const float* ln_s = (const float*)d_in[3];
  const float* ln_b = (const float*)d_in[4];
  const float* w_is = (const float*)d_in[5];
  const float* b_is = (const float*)d_in[6];
  const float* w_ss = (const float*)d_in[7];
  const float* b_ss = (const float*)d_in[8];
  const float* w_oc = (const float*)d_in[9];
  const float* b_oc = (const float*)d_in[10];
  const float* h0   = (const float*)d_in[11];
  const float* w1   = (const float*)d_in[12];
  const float* b1   = (const float*)d_in[13];
  const float* w2   = (const float*)d_in[14];
  const float* b2   = (const float*)d_in[15];
  const float* wh   = (const float*)d_in[16];
  const float* bh   = (const float*)d_in[17];

  char* ws = (char*)d_ws;
  const size_t ACT = (size_t)16*64*127*128;        // activation elements (bf16)
  ushort_t* AB0 = (ushort_t*)ws;                   // conv out, reused as layer1-left out
  ushort_t* AB1 = AB0 + ACT;                       // layer0 left
  ushort_t* AB2 = AB1 + ACT;                       // layer0 right
  ushort_t* AB3 = AB2 + ACT;                       // layer1 right
  ushort_t* zWp  = AB3 + ACT;                      // packed z weights (bf16)
  ushort_t* wocp = zWp + 262144;                   // packed woc (bf16)
  float* zbias = (float*)(wocp + 32768);
  float* w1T = zbias + 1024;
  float* w2T = w1T + 4096;
  float* whT = w2T + 1024;
  float* kw  = whT + 8192;

  pack_kernel<<<1220, 256, 0, stream>>>(w_is, w_ss, b_is, b_ss, w_oc, w1, w2, wh, ck,
                                        zWp, wocp, zbias, w1T, w2T, whT, kw);
  conv_kernel<<<65024, 256, 0, stream>>>(im, cb, kw, AB0);
  diag_kernel<<<32, 256, 0, stream>>>(AB0, nullptr, AB1, AB2, zWp, wocp, zbias,
                                      ln_s, ln_b, b_oc, h0, 0);
  diag_kernel<<<32, 256, 0, stream>>>(AB1, AB2, AB0, AB3, zWp, wocp, zbias,
                                      ln_s, ln_b, b_oc, h0, 1);
  head_kernel<<<1024, 256, 0, stream>>>(AB0, AB3, w1T, b1, w2T, b2, whT, bh,
                                        (float*)d_out);
}

// Round 3
// 1326.702 us; speedup vs baseline: 1.1646x; 1.1646x over previous
//
#include <hip/hip_runtime.h>

typedef unsigned short ushort_t;
typedef unsigned int uint_t;
typedef __attribute__((ext_vector_type(8))) short s8bf;   // 8 x bf16 MFMA fragment
typedef __attribute__((ext_vector_type(4))) float f32x4;  // MFMA accumulator

#define N2 127
#define ACT ((size_t)16*64*127*128)     // activation elements (bf16)
#define HNE ((size_t)16*64*127*64)      // hn elements (bf16)

__device__ inline float bf_lo(uint_t v){ return __uint_as_float(v << 16); }
__device__ inline float bf_hi(uint_t v){ return __uint_as_float(v & 0xffff0000u); }
__device__ inline ushort_t f2bf(float f){
  uint_t u = __float_as_uint(f);
  uint_t r = ((u >> 16) & 1u) + 0x7fffu;  // RNE
  return (ushort_t)((u + r) >> 16);
}
__device__ inline float bf2f(ushort_t h){ return __uint_as_float(((uint_t)h) << 16); }
__device__ inline float frcp(float x){ return __builtin_amdgcn_rcpf(x); }
__device__ inline float sigm(float x){ return frcp(1.f + __expf(-x)); }
__device__ inline float tanhf_(float x){
  float xc = fminf(fmaxf(x, -15.f), 15.f);
  float e = __expf(2.f * xc);
  return (e - 1.f) * frcp(e + 1.f);
}
__device__ inline void unpack8(uint4 u, float* x){
  x[0]=bf_lo(u.x); x[1]=bf_hi(u.x); x[2]=bf_lo(u.y); x[3]=bf_hi(u.y);
  x[4]=bf_lo(u.z); x[5]=bf_hi(u.z); x[6]=bf_lo(u.w); x[7]=bf_hi(u.w);
}
__device__ inline f32x4 zero4(){ f32x4 v; v[0]=0.f; v[1]=0.f; v[2]=0.f; v[3]=0.f; return v; }

__device__ inline void rowstats(const float* xr, float& mu, float& rstd){
  float s0=0.f, q0=0.f;
#pragma unroll
  for (int k = 0; k < 32; k++){ s0 += xr[k]; q0 += xr[k]*xr[k]; }
  s0 += __shfl_xor(s0, 1); q0 += __shfl_xor(q0, 1);
  s0 += __shfl_xor(s0, 2); q0 += __shfl_xor(q0, 2);
  mu = s0 * 0.0078125f;
  float var = q0 * 0.0078125f - mu*mu;
  rstd = rsqrtf(var + 1e-6f);
}

// ---------------------------------------------------------------------------
// Pack weights into MFMA B-fragment order.
// zWp: wss (K=128: k 0-63 = wss[.,0] (hprev), 64-127 = wss[.,1] (h)), N=256.
// wisp: wis K=128, N=256.  wocp: K=64, N=128.
// Fragment addr: ((kk*NCTG + ctg)*64 + lane)*8 + e, k = kk*32 + quad*8 + e,
// n = ctg*16 + l16.
// ---------------------------------------------------------------------------
__global__ void pack_kernel(const float* __restrict__ w_is, const float* __restrict__ w_ss,
                            const float* __restrict__ b_is, const float* __restrict__ b_ss,
                            const float* __restrict__ w_oc, const float* __restrict__ w1,
                            const float* __restrict__ w2, const float* __restrict__ wh,
                            const float* __restrict__ ck,
                            ushort_t* __restrict__ zWp, ushort_t* __restrict__ wisp,
                            ushort_t* __restrict__ wocp,
                            float* __restrict__ zbias, float* __restrict__ w1T,
                            float* __restrict__ w2T, float* __restrict__ whT,
                            float* __restrict__ kw)
{
  int idx = blockIdx.x * 256 + threadIdx.x;
  if (idx < 131072){                        // zWp (wss): 4 ld x 32768
    int ld = idx >> 15; int r = idx & 32767;
    int e = r & 7, lane = (r >> 3) & 63, ctg = (r >> 9) & 15, kk = r >> 13;
    int k = kk*32 + ((lane >> 4) & 3)*8 + e;
    int n = ctg*16 + (lane & 15);
    float v;
    if (k < 64) v = w_ss[(((size_t)ld*2 + 0)*64 + k)*256 + n];
    else        v = w_ss[(((size_t)ld*2 + 1)*64 + (k-64))*256 + n];
    zWp[idx] = f2bf(v);
  } else if (idx < 262144){                 // wisp: 4 ld x 32768
    int r0 = idx - 131072;
    int ld = r0 >> 15; int r = r0 & 32767;
    int e = r & 7, lane = (r >> 3) & 63, ctg = (r >> 9) & 15, kk = r >> 13;
    int k = kk*32 + ((lane >> 4) & 3)*8 + e;
    int n = ctg*16 + (lane & 15);
    wisp[r0] = f2bf(w_is[((size_t)ld*128 + k)*256 + n]);
  } else if (idx < 294912){                 // wocp: 4 x 8192
    int r0 = idx - 262144;
    int ld = r0 >> 13; int r = r0 & 8191;
    int e = r & 7, lane = (r >> 3) & 63, ctg = (r >> 9) & 7, kk = (r >> 12) & 1;
    int k = kk*32 + ((lane >> 4) & 3)*8 + e;
    int n = ctg*16 + (lane & 15);
    wocp[r0] = f2bf(w_oc[((size_t)ld*64 + k)*128 + n]);
  } else if (idx < 295936){                 // fused z bias
    int r = idx - 294912;
    zbias[r] = b_is[r] + b_ss[r];
  } else if (idx < 300032){                 // w_out1^T (32,128)
    int r = idx - 295936;
    int c = r >> 7, k = r & 127;
    w1T[r] = w1[k*32 + c];
  } else if (idx < 301056){                 // w_out2^T (32,32)
    int r = idx - 300032;
    int c = r >> 5, k = r & 31;
    w2T[r] = w2[k*32 + c];
  } else if (idx < 309248){                 // w_head^T (256,32)
    int r = idx - 301056;
    int o = r >> 5, k = r & 31;
    whT[r] = wh[k*256 + o];
  } else if (idx < 312320){                 // 24 live conv taps x 128 ch
    int r = idx - 309248;
    int tau = r >> 7, ch = r & 127;
    int di, dj;
    if (tau < 21){ di = tau/7 - 3; dj = tau%7 - 3; } else { di = 0; dj = tau - 24; }
    kw[r] = ck[((di+3)*7 + (dj+3))*128 + ch];
  }
}

// ---------------------------------------------------------------------------
// Masked 7x7 conv on the implicit skewed image. Output bf16 (B,64,127,128).
// ---------------------------------------------------------------------------
__global__ __launch_bounds__(256) void conv_kernel(const float* __restrict__ im,
                const float* __restrict__ cb, const float* __restrict__ kw,
                ushort_t* __restrict__ out)
{
  int tid = threadIdx.x;
  int p = blockIdx.x*2 + (tid >> 7);
  int ch = tid & 127;
  int b = p / (64*N2); int rem = p - b*(64*N2);
  int i = rem / N2; int j = rem - i*N2;
  int base = j - i;
  float acc = cb[ch];
#pragma unroll
  for (int tau = 0; tau < 24; tau++){
    int di = (tau < 21) ? (tau/7 - 3) : 0;
    int dj = (tau < 21) ? (tau%7 - 3) : (tau - 24);
    int ii = i + di;
    int jx = base + dj - di;
    if (ii >= 0 && jx >= 0 && jx < 64)
      acc += im[(b*64 + ii)*64 + jx] * kw[tau*128 + ch];
  }
  out[(size_t)p*128 + ch] = f2bf(acc);
}

// ---------------------------------------------------------------------------
// write_frags: XN (64x128 bf16 tile, stride 136) -> global fragment file
// (16 KB per (b,j) tile) in diag's A-fragment order.
// ---------------------------------------------------------------------------
__device__ inline void write_frags(const ushort_t* __restrict__ XN,
                                   ushort_t* __restrict__ dst, int tid){
  int lane = tid & 63, kkq = tid >> 6;
  int quad = (lane >> 4) & 3, l16 = lane & 15;
#pragma unroll
  for (int rt = 0; rt < 4; rt++){
    uint4 v = *(const uint4*)&XN[(size_t)(rt*16 + l16)*136 + kkq*32 + quad*8];
    *(uint4*)(dst + (size_t)((kkq*4 + rt)*64 + lane)*8) = v;
  }
}

__device__ inline void ln_to_XN(ushort_t* __restrict__ XN, int row, int lq,
                                const float* xr, float mu, float rstd,
                                const float* __restrict__ ln_s,
                                const float* __restrict__ ln_b, int ld){
#pragma unroll
  for (int k = 0; k < 32; k++){
    int c = lq*32 + k;
    float xn = (xr[k] - mu)*rstd*ln_s[ld*128 + c] + ln_b[ld*128 + c];
    XN[(size_t)row*136 + c] = f2bf(xn);
  }
}

// ---------------------------------------------------------------------------
// Stage kernel (parallel, 2032 blocks = (b,j)).
// mode 0: xn = LN(Xbuf; layer lnlyr, both dirs) -> xnf fragment files.
// mode 1: X' = [hnL@wocL+bocL+LN(X;wl,L)] + shift_m[...R]; X'->Xbuf (in place,
//         own j-slice only); then LN(X'; lnlyr both dirs) -> xnf frags.
// mode 2: like mode 1 but stops after writing X' (the head input).
// ---------------------------------------------------------------------------
__global__ __launch_bounds__(256, 2) void stage_kernel(
    int mode, int woclyr, int lnlyr,
    ushort_t* __restrict__ Xbuf,
    const ushort_t* __restrict__ hnL, const ushort_t* __restrict__ hnR,
    const ushort_t* __restrict__ wocp, const float* __restrict__ b_oc,
    const float* __restrict__ ln_s, const float* __restrict__ ln_b,
    ushort_t* __restrict__ xnfL, ushort_t* __restrict__ xnfR)
{
  __shared__ __align__(16) float Xout[64*132];     // 33792 B
  __shared__ __align__(16) ushort_t XN[64*136];    // 17408 B
  __shared__ __align__(16) ushort_t XNh[64*72];    //  9216 B   (total 60416)

  const int tid = threadIdx.x;
  const int bj = blockIdx.x;
  const int b = bj / 127, j = bj - b*127;
  const int w = tid >> 6, lane = tid & 63, quad = (lane >> 4) & 3, l16 = lane & 15;
  const int row = tid >> 2, lq = tid & 3;

  // this thread's X row-quarter (bf16 -> fp32 regs)
  float xr[32];
  {
    const uint4* p = (const uint4*)(Xbuf + ((size_t)(b*64 + row)*N2 + j)*128 + lq*32);
    unpack8(p[0], xr); unpack8(p[1], xr+8); unpack8(p[2], xr+16); unpack8(p[3], xr+24);
  }
  float mu, rstd;
  rowstats(xr, mu, rstd);

  if (mode == 0){
    ln_to_XN(XN, row, lq, xr, mu, rstd, ln_s, ln_b, lnlyr*2 + 0);
    __syncthreads();
    write_frags(XN, xnfL + (size_t)bj*8192, tid);
    __syncthreads();
    ln_to_XN(XN, row, lq, xr, mu, rstd, ln_s, ln_b, lnlyr*2 + 1);
    __syncthreads();
    write_frags(XN, xnfR + (size_t)bj*8192, tid);
    return;
  }

  // ---- woc epilogues for both directions, combined with m-shift ----
#pragma unroll 1
  for (int s = 0; s < 2; s++){
    const int ld = woclyr*2 + s;
    ln_to_XN(XN, row, lq, xr, mu, rstd, ln_s, ln_b, ld);   // residual xn
    {
      const ushort_t* hp = s ? hnR : hnL;
      const uint4* p = (const uint4*)(hp + ((size_t)(b*64 + row)*N2 + j)*64 + lq*16);
      *(uint4*)&XNh[(size_t)row*72 + lq*16]     = p[0];
      *(uint4*)&XNh[(size_t)row*72 + lq*16 + 8] = p[1];
    }
    __syncthreads();
    s8bf bw[2][2];
#pragma unroll
    for (int kk = 0; kk < 2; kk++)
#pragma unroll
      for (int jt = 0; jt < 2; jt++)
        bw[kk][jt] = *(const s8bf*)(wocp + (size_t)ld*8192 + (size_t)(((kk*8 + (2*w + jt))*64 + lane)*8));
    f32x4 a2[4][2];
#pragma unroll
    for (int rt = 0; rt < 4; rt++){ a2[rt][0] = zero4(); a2[rt][1] = zero4(); }
#pragma unroll
    for (int kk = 0; kk < 2; kk++)
#pragma unroll
      for (int rt = 0; rt < 4; rt++){
        s8bf a = *(const s8bf*)&XNh[(size_t)(rt*16 + l16)*72 + kk*32 + quad*8];
#pragma unroll
        for (int jt = 0; jt < 2; jt++)
          a2[rt][jt] = __builtin_amdgcn_mfma_f32_16x16x32_bf16(a, bw[kk][jt], a2[rt][jt], 0, 0, 0);
      }
    const float bv0 = b_oc[ld*128 + 32*w + l16];
    const float bv1 = b_oc[ld*128 + 32*w + 16 + l16];
#pragma unroll
    for (int rt = 0; rt < 4; rt++)
#pragma unroll
      for (int jt = 0; jt < 2; jt++){
        int col = 32*w + 16*jt + l16;
        float bv = jt ? bv1 : bv0;
#pragma unroll
        for (int r = 0; r < 4; r++){
          int rr = rt*16 + quad*4 + r;
          float v = a2[rt][jt][r] + bv + bf2f(XN[(size_t)rr*136 + col]);
          if (s == 0) Xout[(size_t)rr*132 + col] = v;
          else if (rr < 63) Xout[(size_t)(rr + 1)*132 + col] += v;  // m-shift; row 0 = left only
        }
      }
    __syncthreads();
  }

  // ---- write combined X back to Xbuf (own j-slice; reads all done) ----
  float xo[32];
#pragma unroll
  for (int k = 0; k < 32; k++) xo[k] = Xout[(size_t)row*132 + lq*32 + k];
  {
    uint_t o[16];
#pragma unroll
    for (int k = 0; k < 16; k++){
      ushort_t lo = f2bf(xo[2*k]);
      ushort_t hi = f2bf(xo[2*k + 1]);
      o[k] = (uint_t)lo | ((uint_t)hi << 16);
    }
    uint4* dst = (uint4*)(Xbuf + ((size_t)(b*64 + row)*N2 + j)*128 + lq*32);
#pragma unroll
    for (int q2 = 0; q2 < 4; q2++) dst[q2] = make_uint4(o[q2*4], o[q2*4+1], o[q2*4+2], o[q2*4+3]);
  }
  if (mode == 2) return;

  // ---- LN for the next layer -> fragment files ----
  float mu2, rstd2;
  rowstats(xo, mu2, rstd2);
  ln_to_XN(XN, row, lq, xo, mu2, rstd2, ln_s, ln_b, lnlyr*2 + 0);
  __syncthreads();
  write_frags(XN, xnfL + (size_t)bj*8192, tid);
  __syncthreads();
  ln_to_XN(XN, row, lq, xo, mu2, rstd2, ln_s, ln_b, lnlyr*2 + 1);
  __syncthreads();
  write_frags(XN, xnfR + (size_t)bj*8192, tid);
}

// ---------------------------------------------------------------------------
// Diagonal LSTM recurrence: z = xn@wis + [hprev|h]@wss + zbias; gates; h.
// One block per (b,d); 127 steps; 2 barriers/step. xn read as pre-swizzled
// A-fragments (prefetched 1 step ahead); weights resident in registers.
// ---------------------------------------------------------------------------
__global__ __launch_bounds__(256, 1) void diag_kernel(
    const ushort_t* __restrict__ xnfL, const ushort_t* __restrict__ xnfR,
    ushort_t* __restrict__ hnL, ushort_t* __restrict__ hnR,
    const ushort_t* __restrict__ zWp, const ushort_t* __restrict__ wisp,
    const float* __restrict__ zbias, const float* __restrict__ h0, int layer)
{
  __shared__ ushort_t A[64][136];     // [hprev(0:64) | h(64:128)], +8 pad

  const int tid = threadIdx.x;
  const int b = blockIdx.x & 15;
  const int d = blockIdx.x >> 4;
  const int ld = layer*2 + d;
  const ushort_t* xnf = d ? xnfR : xnfL;
  ushort_t* hp = d ? hnR : hnL;

  const int w = tid >> 6;
  const int lane = tid & 63;
  const int quad = lane >> 4;
  const int l16 = lane & 15;
  const int cg = w*16 + l16;

  s8bf bis[4][4], bss[4][4];
#pragma unroll
  for (int kk = 0; kk < 4; kk++)
#pragma unroll
    for (int ct = 0; ct < 4; ct++){
      size_t fo = (size_t)(((kk*16 + (w + 4*ct))*64 + lane)*8);
      bis[kk][ct] = *(const s8bf*)(wisp + (size_t)ld*32768 + fo);
      bss[kk][ct] = *(const s8bf*)(zWp  + (size_t)ld*32768 + fo);
    }
  const float zbF = zbias[ld*256 + cg];
  const float zbI = zbias[ld*256 + 64 + cg];
  const float zbO = zbias[ld*256 + 128 + cg];
  const float zbG = zbias[ld*256 + 192 + cg];

  float c_reg[16];
#pragma unroll
  for (int k = 0; k < 16; k++) c_reg[k] = 0.f;

  { // init h carry = h0 broadcast; hprev row0 = 0
    int r2 = tid >> 2, q2 = tid & 3;
    const float* h0p = h0 + ld*64;
#pragma unroll
    for (int k = 0; k < 16; k++){
      int c = q2*16 + k;
      ushort_t hb = f2bf(h0p[c]);
      A[r2][64 + c] = hb;
      A[r2][c] = (r2 == 0) ? (ushort_t)0 : hb;
    }
  }
  __syncthreads();

  uint4 xf[4][4];
  {
    int j0 = d ? 126 : 0;
    const ushort_t* base = xnf + ((size_t)(b*127 + j0))*8192;
#pragma unroll
    for (int kk = 0; kk < 4; kk++)
#pragma unroll
      for (int rt = 0; rt < 4; rt++)
        xf[kk][rt] = *(const uint4*)(base + (size_t)((kk*4 + rt)*64 + lane)*8);
  }

#pragma unroll 1
  for (int t = 0; t < 127; t++){
    const int j = d ? (126 - t) : t;
    f32x4 acc[4][4];
#pragma unroll
    for (int rt = 0; rt < 4; rt++)
#pragma unroll
      for (int ct = 0; ct < 4; ct++) acc[rt][ct] = zero4();

    // xn @ wis (independent of the recurrence)
#pragma unroll
    for (int kk = 0; kk < 4; kk++)
#pragma unroll
      for (int rt = 0; rt < 4; rt++){
        s8bf a = *(const s8bf*)&xf[kk][rt];
#pragma unroll
        for (int ct = 0; ct < 4; ct++)
          acc[rt][ct] = __builtin_amdgcn_mfma_f32_16x16x32_bf16(a, bis[kk][ct], acc[rt][ct], 0, 0, 0);
      }

    // prefetch next step's xn fragments
    if (t < 126){
      int jn = d ? (126 - (t+1)) : (t+1);
      const ushort_t* base = xnf + ((size_t)(b*127 + jn))*8192;
#pragma unroll
      for (int kk = 0; kk < 4; kk++)
#pragma unroll
        for (int rt = 0; rt < 4; rt++)
          xf[kk][rt] = *(const uint4*)(base + (size_t)((kk*4 + rt)*64 + lane)*8);
    }

    // [hprev|h] @ wss (A written last step; barrier at end of loop body)
#pragma unroll
    for (int kk = 0; kk < 4; kk++){
      s8bf af[4];
#pragma unroll
      for (int rt = 0; rt < 4; rt++)
        af[rt] = *(const s8bf*)&A[rt*16 + l16][kk*32 + quad*8];
#pragma unroll
      for (int rt = 0; rt < 4; rt++)
#pragma unroll
        for (int ct = 0; ct < 4; ct++)
          acc[rt][ct] = __builtin_amdgcn_mfma_f32_16x16x32_bf16(af[rt], bss[kk][ct], acc[rt][ct], 0, 0, 0);
    }
    __syncthreads(); // all LDS reads of A complete

#pragma unroll
    for (int rt = 0; rt < 4; rt++){
#pragma unroll
      for (int r = 0; r < 4; r++){
        int idx = rt*4 + r;
        float fg = sigm(acc[rt][0][r] + zbF);
        float ig = sigm(acc[rt][1][r] + zbI);
        float og = sigm(acc[rt][2][r] + zbO);
        float gg = tanhf_(acc[rt][3][r] + zbG);
        float cn = fg*c_reg[idx] + ig*gg;
        c_reg[idx] = cn;
        float hn = og * tanhf_(cn);
        int rr = rt*16 + quad*4 + r;
        ushort_t hb = f2bf(hn);
        A[rr][64 + cg] = hb;
        if (rr < 63) A[rr + 1][cg] = hb;
        hp[((size_t)(b*64 + rr)*N2 + j)*64 + cg] = hb;
      }
    }
    __syncthreads(); // new h/hprev visible
  }
}

// ---------------------------------------------------------------------------
// Head: unskew + (128->32)->(32->32)->(32->256), fp32 vector math.
// ---------------------------------------------------------------------------
__global__ __launch_bounds__(256) void head_kernel(
    const ushort_t* __restrict__ xfin,
    const float* __restrict__ w1T, const float* __restrict__ b1,
    const float* __restrict__ w2T, const float* __restrict__ b2,
    const float* __restrict__ whT, const float* __restrict__ bh,
    float* __restrict__ out)
{
  __shared__ float xf[64][132];
  __shared__ float v1[64][36];
  __shared__ float v2[64][36];
  int tid = threadIdx.x;
  int b = blockIdx.x >> 6, i = blockIdx.x & 63;
  {
    int jj = tid >> 2, q = tid & 3;
    size_t base = ((size_t)(b*64 + i)*N2 + (i + jj))*128 + q*32;  // unskew
    const uint4* pL = (const uint4*)(xfin + base);
    float x[32];
    unpack8(pL[0], x); unpack8(pL[1], x+8); unpack8(pL[2], x+16); unpack8(pL[3], x+24);
#pragma unroll
    for (int k = 0; k < 32; k++) xf[jj][q*32 + k] = x[k];
  }
  __syncthreads();
  {
    int c1 = tid & 31, jg = tid >> 5;
    float wr[128];
    const float4* wp = (const float4*)(w1T + c1*128);
#pragma unroll
    for (int kk = 0; kk < 32; kk++) ((float4*)wr)[kk] = wp[kk];
#pragma unroll 1
    for (int jj2 = 0; jj2 < 8; jj2++){
      int jr = jg*8 + jj2;
      float a0=0.f,a1=0.f,a2=0.f,a3=0.f;
#pragma unroll
      for (int kk = 0; kk < 32; kk++){
        float4 xv = *(const float4*)&xf[jr][kk*4];
        a0 += xv.x*wr[kk*4]; a1 += xv.y*wr[kk*4+1]; a2 += xv.z*wr[kk*4+2]; a3 += xv.w*wr[kk*4+3];
      }
      v1[jr][c1] = b1[c1] + (a0+a1)+(a2+a3);
    }
  }
  __syncthreads();
  {
    int c2 = tid & 31, jg = tid >> 5;
    float wr[32];
    const float4* wp = (const float4*)(w2T + c2*32);
#pragma unroll
    for (int kk = 0; kk < 8; kk++) ((float4*)wr)[kk] = wp[kk];
#pragma unroll 1
    for (int jj2 = 0; jj2 < 8; jj2++){
      int jr = jg*8 + jj2;
      float a0=0.f,a1=0.f,a2=0.f,a3=0.f;
#pragma unroll
      for (int kk = 0; kk < 8; kk++){
        float4 xv = *(const float4*)&v1[jr][kk*4];
        a0 += xv.x*wr[kk*4]; a1 += xv.y*wr[kk*4+1]; a2 += xv.z*wr[kk*4+2]; a3 += xv.w*wr[kk*4+3];
      }
      v2[jr][c2] = b2[c2] + (a0+a1)+(a2+a3);
    }
  }
  __syncthreads();
  {
    int o = tid;
    float wr[32];
    const float4* wp = (const float4*)(whT + o*32);
#pragma unroll
    for (int kk = 0; kk < 8; kk++) ((float4*)wr)[kk] = wp[kk];
    float bo = bh[o];
#pragma unroll 1
    for (int jr = 0; jr < 64; jr++){
      float a0=0.f,a1=0.f,a2=0.f,a3=0.f;
#pragma unroll
      for (int kk = 0; kk < 8; kk++){
        float4 xv = *(const float4*)&v2[jr][kk*4];
        a0 += xv.x*wr[kk*4]; a1 += xv.y*wr[kk*4+1]; a2 += xv.z*wr[kk*4+2]; a3 += xv.w*wr[kk*4+3];
      }
      out[(((size_t)b*64 + i)*64 + jr)*256 + o] = bo + (a0+a1)+(a2+a3);
    }
  }
}

// ---------------------------------------------------------------------------
extern "C" void kernel_launch(void* const* d_in, const int* in_sizes, int n_in,
                              void* d_out, int out_size, void* d_ws, size_t ws_size,
                              hipStream_t stream)
{
  const float* im   = (const float*)d_in[0];
  const float* ck   = (const float*)d_in[1];
  const float* cb   = (const float*)d_in[2];
  const float* ln_s = (const float*)d_in[3];
  const float* ln_b = (const float*)d_in[4];
  const float* w_is = (const float*)d_in[5];
  const float* b_is = (const float*)d_in[6];
  const float* w_ss = (const float*)d_in[7];
  const float* b_ss = (const float*)d_in[8];
  const float* w_oc = (const float*)d_in[9];
  const float* b_oc = (const float*)d_in[10];
  const float* h0   = (const float*)d_in[11];
  const float* w1   = (const float*)d_in[12];
  const float* b1   = (const float*)d_in[13];
  const float* w2   = (const float*)d_in[14];
  const float* b2   = (const float*)d_in[15];
  const float* wh   = (const float*)d_in[16];
  const float* bh   = (const float*)d_in[17];

  // Workspace layout: 133,828,608 B total (== Round-1's proven footprint).
  ushort_t* Xbuf = (ushort_t*)d_ws;        // X0 -> X1 (aliased) -> xfin
  ushort_t* xnfL = Xbuf + ACT;             // xn fragment files (per layer, overwritten)
  ushort_t* xnfR = xnfL + ACT;
  ushort_t* hnL  = xnfR + ACT;
  ushort_t* hnR  = hnL + HNE;
  ushort_t* zWp  = hnR + HNE;              // wss frags  (131072 el)
  ushort_t* wisp = zWp + 131072;           // wis frags  (131072 el)
  ushort_t* wocp = wisp + 131072;          // woc frags  (32768 el)
  float* zbias = (float*)(wocp + 32768);
  float* w1T   = zbias + 1024;
  float* w2T   = w1T + 4096;
  float* whT   = w2T + 1024;
  float* kw    = whT + 8192;

  pack_kernel<<<1220, 256, 0, stream>>>(w_is, w_ss, b_is, b_ss, w_oc, w1, w2, wh, ck,
                                        zWp, wisp, wocp, zbias, w1T, w2T, whT, kw);
  conv_kernel<<<65024, 256, 0, stream>>>(im, cb, kw, Xbuf);
  stage_kernel<<<2032, 256, 0, stream>>>(0, 0, 0, Xbuf, nullptr, nullptr,
                                         wocp, b_oc, ln_s, ln_b, xnfL, xnfR);
  diag_kernel<<<32, 256, 0, stream>>>(xnfL, xnfR, hnL, hnR, zWp, wisp, zbias, h0, 0);
  stage_kernel<<<2032, 256, 0, stream>>>(1, 0, 1, Xbuf, hnL, hnR,
                                         wocp, b_oc, ln_s, ln_b, xnfL, xnfR);
  diag_kernel<<<32, 256, 0, stream>>>(xnfL, xnfR, hnL, hnR, zWp, wisp, zbias, h0, 1);
  stage_kernel<<<2032, 256, 0, stream>>>(2, 1, 0, Xbuf, hnL, hnR,
                                         wocp, b_oc, ln_s, ln_b, xnfL, xnfR);
  head_kernel<<<1024, 256, 0, stream>>>(Xbuf, w1T, b1, w2T, b2, whT, bh, (float*)d_out);
}

// Round 4
// 1105.122 us; speedup vs baseline: 1.3981x; 1.2005x over previous
//
#include <hip/hip_runtime.h>

typedef unsigned short ushort_t;
typedef unsigned int uint_t;
typedef __attribute__((ext_vector_type(8))) short s8bf;   // 8 x bf16 MFMA fragment
typedef __attribute__((ext_vector_type(4))) float f32x4;  // MFMA accumulator

#define N2 127
#define ACT ((size_t)16*64*127*128)     // activation elements (bf16)
#define HNE ((size_t)16*64*127*64)      // hn elements (bf16)

__device__ inline float bf_lo(uint_t v){ return __uint_as_float(v << 16); }
__device__ inline float bf_hi(uint_t v){ return __uint_as_float(v & 0xffff0000u); }
__device__ inline ushort_t f2bf(float f){
  uint_t u = __float_as_uint(f);
  uint_t r = ((u >> 16) & 1u) + 0x7fffu;  // RNE
  return (ushort_t)((u + r) >> 16);
}
__device__ inline float bf2f(ushort_t h){ return __uint_as_float(((uint_t)h) << 16); }
__device__ inline float frcp(float x){ return __builtin_amdgcn_rcpf(x); }
__device__ inline float sigm(float x){ return frcp(1.f + __expf(-x)); }
__device__ inline float tanhf_(float x){
  // 1 - 2/(1+e^{2x}); saturates correctly for |x| large via inf/0, no clamp
  float e = __expf(2.f * x);
  return 1.f - 2.f * frcp(1.f + e);
}
__device__ inline void unpack8(uint4 u, float* x){
  x[0]=bf_lo(u.x); x[1]=bf_hi(u.x); x[2]=bf_lo(u.y); x[3]=bf_hi(u.y);
  x[4]=bf_lo(u.z); x[5]=bf_hi(u.z); x[6]=bf_lo(u.w); x[7]=bf_hi(u.w);
}
__device__ inline f32x4 zero4(){ f32x4 v; v[0]=0.f; v[1]=0.f; v[2]=0.f; v[3]=0.f; return v; }
__device__ inline f32x4 splat4(float s){ f32x4 v; v[0]=s; v[1]=s; v[2]=s; v[3]=s; return v; }

__device__ inline void rowstats(const float* xr, float& mu, float& rstd){
  float s0=0.f, q0=0.f;
#pragma unroll
  for (int k = 0; k < 32; k++){ s0 += xr[k]; q0 += xr[k]*xr[k]; }
  s0 += __shfl_xor(s0, 1); q0 += __shfl_xor(q0, 1);
  s0 += __shfl_xor(s0, 2); q0 += __shfl_xor(q0, 2);
  mu = s0 * 0.0078125f;
  float var = q0 * 0.0078125f - mu*mu;
  rstd = rsqrtf(var + 1e-6f);
}

// ---------------------------------------------------------------------------
// Pack weights into MFMA B-fragment order.
// zWp: wss (K=128: k 0-63 = wss[.,0] (hprev), 64-127 = wss[.,1] (h)), N=256.
// wisp: wis K=128, N=256.  wocp: K=64, N=128.
// Fragment addr: ((kk*NCTG + ctg)*64 + lane)*8 + e, k = kk*32 + quad*8 + e,
// n = ctg*16 + l16.
// ---------------------------------------------------------------------------
__global__ void pack_kernel(const float* __restrict__ w_is, const float* __restrict__ w_ss,
                            const float* __restrict__ b_is, const float* __restrict__ b_ss,
                            const float* __restrict__ w_oc, const float* __restrict__ w1,
                            const float* __restrict__ w2, const float* __restrict__ wh,
                            const float* __restrict__ ck,
                            ushort_t* __restrict__ zWp, ushort_t* __restrict__ wisp,
                            ushort_t* __restrict__ wocp,
                            float* __restrict__ zbias, float* __restrict__ w1T,
                            float* __restrict__ w2T, float* __restrict__ whT,
                            float* __restrict__ kw)
{
  int idx = blockIdx.x * 256 + threadIdx.x;
  if (idx < 131072){                        // zWp (wss): 4 ld x 32768
    int ld = idx >> 15; int r = idx & 32767;
    int e = r & 7, lane = (r >> 3) & 63, ctg = (r >> 9) & 15, kk = r >> 13;
    int k = kk*32 + ((lane >> 4) & 3)*8 + e;
    int n = ctg*16 + (lane & 15);
    float v;
    if (k < 64) v = w_ss[(((size_t)ld*2 + 0)*64 + k)*256 + n];
    else        v = w_ss[(((size_t)ld*2 + 1)*64 + (k-64))*256 + n];
    zWp[idx] = f2bf(v);
  } else if (idx < 262144){                 // wisp: 4 ld x 32768
    int r0 = idx - 131072;
    int ld = r0 >> 15; int r = r0 & 32767;
    int e = r & 7, lane = (r >> 3) & 63, ctg = (r >> 9) & 15, kk = r >> 13;
    int k = kk*32 + ((lane >> 4) & 3)*8 + e;
    int n = ctg*16 + (lane & 15);
    wisp[r0] = f2bf(w_is[((size_t)ld*128 + k)*256 + n]);
  } else if (idx < 294912){                 // wocp: 4 x 8192
    int r0 = idx - 262144;
    int ld = r0 >> 13; int r = r0 & 8191;
    int e = r & 7, lane = (r >> 3) & 63, ctg = (r >> 9) & 7, kk = (r >> 12) & 1;
    int k = kk*32 + ((lane >> 4) & 3)*8 + e;
    int n = ctg*16 + (lane & 15);
    wocp[r0] = f2bf(w_oc[((size_t)ld*64 + k)*128 + n]);
  } else if (idx < 295936){                 // fused z bias
    int r = idx - 294912;
    zbias[r] = b_is[r] + b_ss[r];
  } else if (idx < 300032){                 // w_out1^T (32,128)
    int r = idx - 295936;
    int c = r >> 7, k = r & 127;
    w1T[r] = w1[k*32 + c];
  } else if (idx < 301056){                 // w_out2^T (32,32)
    int r = idx - 300032;
    int c = r >> 5, k = r & 31;
    w2T[r] = w2[k*32 + c];
  } else if (idx < 309248){                 // w_head^T (256,32)
    int r = idx - 301056;
    int o = r >> 5, k = r & 31;
    whT[r] = wh[k*256 + o];
  } else if (idx < 312320){                 // 24 live conv taps x 128 ch
    int r = idx - 309248;
    int tau = r >> 7, ch = r & 127;
    int di, dj;
    if (tau < 21){ di = tau/7 - 3; dj = tau%7 - 3; } else { di = 0; dj = tau - 24; }
    kw[r] = ck[((di+3)*7 + (dj+3))*128 + ch];
  }
}

// ---------------------------------------------------------------------------
// Masked 7x7 conv on the implicit skewed image. Output bf16 (B,64,127,128).
// ---------------------------------------------------------------------------
__global__ __launch_bounds__(256) void conv_kernel(const float* __restrict__ im,
                const float* __restrict__ cb, const float* __restrict__ kw,
                ushort_t* __restrict__ out)
{
  int tid = threadIdx.x;
  int p = blockIdx.x*2 + (tid >> 7);
  int ch = tid & 127;
  int b = p / (64*N2); int rem = p - b*(64*N2);
  int i = rem / N2; int j = rem - i*N2;
  int base = j - i;
  float acc = cb[ch];
#pragma unroll
  for (int tau = 0; tau < 24; tau++){
    int di = (tau < 21) ? (tau/7 - 3) : 0;
    int dj = (tau < 21) ? (tau%7 - 3) : (tau - 24);
    int ii = i + di;
    int jx = base + dj - di;
    if (ii >= 0 && jx >= 0 && jx < 64)
      acc += im[(b*64 + ii)*64 + jx] * kw[tau*128 + ch];
  }
  out[(size_t)p*128 + ch] = f2bf(acc);
}

// ---------------------------------------------------------------------------
// write_frags: XN (64x128 bf16 tile, stride 136) -> global fragment file
// (16 KB per (b,j) tile) in diag's A-fragment order.
// ---------------------------------------------------------------------------
__device__ inline void write_frags(const ushort_t* __restrict__ XN,
                                   ushort_t* __restrict__ dst, int tid){
  int lane = tid & 63, kkq = tid >> 6;
  int quad = (lane >> 4) & 3, l16 = lane & 15;
#pragma unroll
  for (int rt = 0; rt < 4; rt++){
    uint4 v = *(const uint4*)&XN[(size_t)(rt*16 + l16)*136 + kkq*32 + quad*8];
    *(uint4*)(dst + (size_t)((kkq*4 + rt)*64 + lane)*8) = v;
  }
}

__device__ inline void ln_to_XN(ushort_t* __restrict__ XN, int row, int lq,
                                const float* xr, float mu, float rstd,
                                const float* __restrict__ ln_s,
                                const float* __restrict__ ln_b, int ld){
#pragma unroll
  for (int k = 0; k < 32; k++){
    int c = lq*32 + k;
    float xn = (xr[k] - mu)*rstd*ln_s[ld*128 + c] + ln_b[ld*128 + c];
    XN[(size_t)row*136 + c] = f2bf(xn);
  }
}

// ---------------------------------------------------------------------------
// Stage kernel (parallel, 2032 blocks = (b,j)).
// mode 0: xn = LN(Xbuf; layer lnlyr, both dirs) -> xnf fragment files.
// mode 1: X' = [hnL@wocL+bocL+LN(X;wl,L)] + shift_m[...R]; X'->Xbuf (in place,
//         own j-slice only); then LN(X'; lnlyr both dirs) -> xnf frags.
// mode 2: like mode 1 but stops after writing X' (the head input).
// ---------------------------------------------------------------------------
__global__ __launch_bounds__(256, 2) void stage_kernel(
    int mode, int woclyr, int lnlyr,
    ushort_t* __restrict__ Xbuf,
    const ushort_t* __restrict__ hnL, const ushort_t* __restrict__ hnR,
    const ushort_t* __restrict__ wocp, const float* __restrict__ b_oc,
    const float* __restrict__ ln_s, const float* __restrict__ ln_b,
    ushort_t* __restrict__ xnfL, ushort_t* __restrict__ xnfR)
{
  __shared__ __align__(16) float Xout[64*132];     // 33792 B
  __shared__ __align__(16) ushort_t XN[64*136];    // 17408 B
  __shared__ __align__(16) ushort_t XNh[64*72];    //  9216 B   (total 60416)

  const int tid = threadIdx.x;
  const int bj = blockIdx.x;
  const int b = bj / 127, j = bj - b*127;
  const int w = tid >> 6, lane = tid & 63, quad = (lane >> 4) & 3, l16 = lane & 15;
  const int row = tid >> 2, lq = tid & 3;

  // this thread's X row-quarter (bf16 -> fp32 regs)
  float xr[32];
  {
    const uint4* p = (const uint4*)(Xbuf + ((size_t)(b*64 + row)*N2 + j)*128 + lq*32);
    unpack8(p[0], xr); unpack8(p[1], xr+8); unpack8(p[2], xr+16); unpack8(p[3], xr+24);
  }
  float mu, rstd;
  rowstats(xr, mu, rstd);

  if (mode == 0){
    ln_to_XN(XN, row, lq, xr, mu, rstd, ln_s, ln_b, lnlyr*2 + 0);
    __syncthreads();
    write_frags(XN, xnfL + (size_t)bj*8192, tid);
    __syncthreads();
    ln_to_XN(XN, row, lq, xr, mu, rstd, ln_s, ln_b, lnlyr*2 + 1);
    __syncthreads();
    write_frags(XN, xnfR + (size_t)bj*8192, tid);
    return;
  }

  // ---- woc epilogues for both directions, combined with m-shift ----
#pragma unroll 1
  for (int s = 0; s < 2; s++){
    const int ld = woclyr*2 + s;
    ln_to_XN(XN, row, lq, xr, mu, rstd, ln_s, ln_b, ld);   // residual xn
    {
      const ushort_t* hp = s ? hnR : hnL;
      const uint4* p = (const uint4*)(hp + ((size_t)(b*64 + row)*N2 + j)*64 + lq*16);
      *(uint4*)&XNh[(size_t)row*72 + lq*16]     = p[0];
      *(uint4*)&XNh[(size_t)row*72 + lq*16 + 8] = p[1];
    }
    __syncthreads();
    s8bf bw[2][2];
#pragma unroll
    for (int kk = 0; kk < 2; kk++)
#pragma unroll
      for (int jt = 0; jt < 2; jt++)
        bw[kk][jt] = *(const s8bf*)(wocp + (size_t)ld*8192 + (size_t)(((kk*8 + (2*w + jt))*64 + lane)*8));
    f32x4 a2[4][2];
#pragma unroll
    for (int rt = 0; rt < 4; rt++){ a2[rt][0] = zero4(); a2[rt][1] = zero4(); }
#pragma unroll
    for (int kk = 0; kk < 2; kk++)
#pragma unroll
      for (int rt = 0; rt < 4; rt++){
        s8bf a = *(const s8bf*)&XNh[(size_t)(rt*16 + l16)*72 + kk*32 + quad*8];
#pragma unroll
        for (int jt = 0; jt < 2; jt++)
          a2[rt][jt] = __builtin_amdgcn_mfma_f32_16x16x32_bf16(a, bw[kk][jt], a2[rt][jt], 0, 0, 0);
      }
    const float bv0 = b_oc[ld*128 + 32*w + l16];
    const float bv1 = b_oc[ld*128 + 32*w + 16 + l16];
#pragma unroll
    for (int rt = 0; rt < 4; rt++)
#pragma unroll
      for (int jt = 0; jt < 2; jt++){
        int col = 32*w + 16*jt + l16;
        float bv = jt ? bv1 : bv0;
#pragma unroll
        for (int r = 0; r < 4; r++){
          int rr = rt*16 + quad*4 + r;
          float v = a2[rt][jt][r] + bv + bf2f(XN[(size_t)rr*136 + col]);
          if (s == 0) Xout[(size_t)rr*132 + col] = v;
          else if (rr < 63) Xout[(size_t)(rr + 1)*132 + col] += v;  // m-shift; row 0 = left only
        }
      }
    __syncthreads();
  }

  // ---- write combined X back to Xbuf (own j-slice; reads all done) ----
  float xo[32];
#pragma unroll
  for (int k = 0; k < 32; k++) xo[k] = Xout[(size_t)row*132 + lq*32 + k];
  {
    uint_t o[16];
#pragma unroll
    for (int k = 0; k < 16; k++){
      ushort_t lo = f2bf(xo[2*k]);
      ushort_t hi = f2bf(xo[2*k + 1]);
      o[k] = (uint_t)lo | ((uint_t)hi << 16);
    }
    uint4* dst = (uint4*)(Xbuf + ((size_t)(b*64 + row)*N2 + j)*128 + lq*32);
#pragma unroll
    for (int q2 = 0; q2 < 4; q2++) dst[q2] = make_uint4(o[q2*4], o[q2*4+1], o[q2*4+2], o[q2*4+3]);
  }
  if (mode == 2) return;

  // ---- LN for the next layer -> fragment files ----
  float mu2, rstd2;
  rowstats(xo, mu2, rstd2);
  ln_to_XN(XN, row, lq, xo, mu2, rstd2, ln_s, ln_b, lnlyr*2 + 0);
  __syncthreads();
  write_frags(XN, xnfL + (size_t)bj*8192, tid);
  __syncthreads();
  ln_to_XN(XN, row, lq, xo, mu2, rstd2, ln_s, ln_b, lnlyr*2 + 1);
  __syncthreads();
  write_frags(XN, xnfR + (size_t)bj*8192, tid);
}

// ---------------------------------------------------------------------------
// Diagonal LSTM recurrence, 512 threads / 8 waves (2 waves/SIMD for overlap).
// Wave w owns row-pair (w>>2) [rows 32*(w>>2)..+31] and col group (w&3).
// acc enters each step holding zxa(t) = xn(t)@wis + zbias (computed during the
// previous step's gate phase); phase A adds [hprev|h]@wss; phase B computes
// gates, writes h, then rebuilds zxa(t+1) (MFMA pipe overlaps the other
// wave's gate VALU) and prefetches xn(t+2).
// ---------------------------------------------------------------------------
__global__ __launch_bounds__(512, 2) void diag_kernel(
    const ushort_t* __restrict__ xnfL, const ushort_t* __restrict__ xnfR,
    ushort_t* __restrict__ hnL, ushort_t* __restrict__ hnR,
    const ushort_t* __restrict__ zWp, const ushort_t* __restrict__ wisp,
    const float* __restrict__ zbias, const float* __restrict__ h0, int layer)
{
  __shared__ ushort_t A[64][136];     // [hprev(0:64) | h(64:128)], +8 pad

  const int tid = threadIdx.x;
  const int b = blockIdx.x & 15;
  const int d = blockIdx.x >> 4;
  const int ld = layer*2 + d;
  const ushort_t* xnf = d ? xnfR : xnfL;
  ushort_t* hp = d ? hnR : hnL;

  const int w = tid >> 6;
  const int lane = tid & 63;
  const int quad = lane >> 4;
  const int l16 = lane & 15;
  const int cgrp = w & 3;             // col group (16 cols per gate)
  const int rpair = w >> 2;           // row-pair (rows 32*rpair .. +31)
  const int cg = cgrp*16 + l16;

  // B fragments: all 4 gates of this wave's col group, wis + wss
  s8bf bss[4][4], bis[4][4];
#pragma unroll
  for (int kk = 0; kk < 4; kk++)
#pragma unroll
    for (int ct = 0; ct < 4; ct++){
      size_t fo = (size_t)(((kk*16 + (cgrp + 4*ct))*64 + lane)*8);
      bss[kk][ct] = *(const s8bf*)(zWp  + (size_t)ld*32768 + fo);
      bis[kk][ct] = *(const s8bf*)(wisp + (size_t)ld*32768 + fo);
    }
  float zb[4];
#pragma unroll
  for (int ct = 0; ct < 4; ct++) zb[ct] = zbias[ld*256 + ct*64 + cg];

  float c_reg[8];
#pragma unroll
  for (int k = 0; k < 8; k++) c_reg[k] = 0.f;

  { // init A: h carry = h0 broadcast; hprev row0 = 0
    int r2 = tid >> 3, q8 = tid & 7;
    const float* h0p = h0 + ld*64;
#pragma unroll
    for (int k = 0; k < 8; k++){
      int c = q8*8 + k;
      ushort_t hb = f2bf(h0p[c]);
      A[r2][64 + c] = hb;
      A[r2][c] = (r2 == 0) ? (ushort_t)0 : hb;
    }
  }

  // xf = xn(0) fragments; compute zxa(0) into acc; then prefetch xn(1)
  const int stp8 = d ? -8192 : 8192;
  const ushort_t* xbase = xnf + ((size_t)b*127 + (d ? 126 : 0))*8192;
  uint4 xf[4][2];
#pragma unroll
  for (int kk = 0; kk < 4; kk++)
#pragma unroll
    for (int rt = 0; rt < 2; rt++)
      xf[kk][rt] = *(const uint4*)(xbase + (size_t)((kk*4 + rpair*2 + rt)*64 + lane)*8);

  f32x4 acc[2][4];
#pragma unroll
  for (int rt = 0; rt < 2; rt++)
#pragma unroll
    for (int ct = 0; ct < 4; ct++) acc[rt][ct] = splat4(zb[ct]);
#pragma unroll
  for (int kk = 0; kk < 4; kk++)
#pragma unroll
    for (int rt = 0; rt < 2; rt++){
      s8bf a = *(const s8bf*)&xf[kk][rt];
#pragma unroll
      for (int ct = 0; ct < 4; ct++)
        acc[rt][ct] = __builtin_amdgcn_mfma_f32_16x16x32_bf16(a, bis[kk][ct], acc[rt][ct], 0, 0, 0);
    }
  const ushort_t* pfp = xbase + stp8;   // next prefetch tile (t=1)
#pragma unroll
  for (int kk = 0; kk < 4; kk++)
#pragma unroll
    for (int rt = 0; rt < 2; rt++)
      xf[kk][rt] = *(const uint4*)(pfp + (size_t)((kk*4 + rpair*2 + rt)*64 + lane)*8);
  pfp += stp8;

  // running hn store pointer (lane base row = rpair*32 + quad*4, col cg)
  const int dj64 = d ? -64 : 64;
  ushort_t* hlane = hp + ((size_t)(b*64 + rpair*32 + quad*4)*N2 + (d ? 126 : 0))*64 + cg;

  __syncthreads();  // A init visible

#pragma unroll 1
  for (int t = 0; t < 127; t++){
    // ---- phase A: acc += [hprev|h] @ wss ----
#pragma unroll
    for (int kk = 0; kk < 4; kk++){
      s8bf af0 = *(const s8bf*)&A[rpair*32 + l16][kk*32 + quad*8];
      s8bf af1 = *(const s8bf*)&A[rpair*32 + 16 + l16][kk*32 + quad*8];
#pragma unroll
      for (int ct = 0; ct < 4; ct++){
        acc[0][ct] = __builtin_amdgcn_mfma_f32_16x16x32_bf16(af0, bss[kk][ct], acc[0][ct], 0, 0, 0);
        acc[1][ct] = __builtin_amdgcn_mfma_f32_16x16x32_bf16(af1, bss[kk][ct], acc[1][ct], 0, 0, 0);
      }
    }
    __syncthreads(); // B1: all ds_reads of A complete

    // ---- phase B: gates (VALU) ----
#pragma unroll
    for (int rt = 0; rt < 2; rt++){
#pragma unroll
      for (int r = 0; r < 4; r++){
        int idx = rt*4 + r;
        float fg = sigm(acc[rt][0][r]);
        float ig = sigm(acc[rt][1][r]);
        float og = sigm(acc[rt][2][r]);
        float gg = tanhf_(acc[rt][3][r]);
        float cn = fg*c_reg[idx] + ig*gg;
        c_reg[idx] = cn;
        float hn = og * tanhf_(cn);
        int rr = (rpair*2 + rt)*16 + quad*4 + r;
        ushort_t hb = f2bf(hn);
        A[rr][64 + cg] = hb;
        if (rr < 63) A[rr + 1][cg] = hb;
        hlane[(size_t)(rt*16 + r)*8128] = hb;
      }
    }
    hlane += dj64;

    // ---- phase B: zxa(t+1) = xn(t+1)@wis + zbias (overlaps other wave's gates)
    if (t < 126){
#pragma unroll
      for (int rt = 0; rt < 2; rt++)
#pragma unroll
        for (int ct = 0; ct < 4; ct++) acc[rt][ct] = splat4(zb[ct]);
#pragma unroll
      for (int kk = 0; kk < 4; kk++)
#pragma unroll
        for (int rt = 0; rt < 2; rt++){
          s8bf a = *(const s8bf*)&xf[kk][rt];
#pragma unroll
          for (int ct = 0; ct < 4; ct++)
            acc[rt][ct] = __builtin_amdgcn_mfma_f32_16x16x32_bf16(a, bis[kk][ct], acc[rt][ct], 0, 0, 0);
        }
      if (t < 125){
#pragma unroll
        for (int kk = 0; kk < 4; kk++)
#pragma unroll
          for (int rt = 0; rt < 2; rt++)
            xf[kk][rt] = *(const uint4*)(pfp + (size_t)((kk*4 + rpair*2 + rt)*64 + lane)*8);
        pfp += stp8;
      }
    }
    __syncthreads(); // B2: new h/hprev visible for next phase A
  }
}

// ---------------------------------------------------------------------------
// Head: unskew + (128->32)->(32->32)->(32->256), fp32 vector math.
// ---------------------------------------------------------------------------
__global__ __launch_bounds__(256) void head_kernel(
    const ushort_t* __restrict__ xfin,
    const float* __restrict__ w1T, const float* __restrict__ b1,
    const float* __restrict__ w2T, const float* __restrict__ b2,
    const float* __restrict__ whT, const float* __restrict__ bh,
    float* __restrict__ out)
{
  __shared__ float xf[64][132];
  __shared__ float v1[64][36];
  __shared__ float v2[64][36];
  int tid = threadIdx.x;
  int b = blockIdx.x >> 6, i = blockIdx.x & 63;
  {
    int jj = tid >> 2, q = tid & 3;
    size_t base = ((size_t)(b*64 + i)*N2 + (i + jj))*128 + q*32;  // unskew
    const uint4* pL = (const uint4*)(xfin + base);
    float x[32];
    unpack8(pL[0], x); unpack8(pL[1], x+8); unpack8(pL[2], x+16); unpack8(pL[3], x+24);
#pragma unroll
    for (int k = 0; k < 32; k++) xf[jj][q*32 + k] = x[k];
  }
  __syncthreads();
  {
    int c1 = tid & 31, jg = tid >> 5;
    float wr[128];
    const float4* wp = (const float4*)(w1T + c1*128);
#pragma unroll
    for (int kk = 0; kk < 32; kk++) ((float4*)wr)[kk] = wp[kk];
#pragma unroll 1
    for (int jj2 = 0; jj2 < 8; jj2++){
      int jr = jg*8 + jj2;
      float a0=0.f,a1=0.f,a2=0.f,a3=0.f;
#pragma unroll
      for (int kk = 0; kk < 32; kk++){
        float4 xv = *(const float4*)&xf[jr][kk*4];
        a0 += xv.x*wr[kk*4]; a1 += xv.y*wr[kk*4+1]; a2 += xv.z*wr[kk*4+2]; a3 += xv.w*wr[kk*4+3];
      }
      v1[jr][c1] = b1[c1] + (a0+a1)+(a2+a3);
    }
  }
  __syncthreads();
  {
    int c2 = tid & 31, jg = tid >> 5;
    float wr[32];
    const float4* wp = (const float4*)(w2T + c2*32);
#pragma unroll
    for (int kk = 0; kk < 8; kk++) ((float4*)wr)[kk] = wp[kk];
#pragma unroll 1
    for (int jj2 = 0; jj2 < 8; jj2++){
      int jr = jg*8 + jj2;
      float a0=0.f,a1=0.f,a2=0.f,a3=0.f;
#pragma unroll
      for (int kk = 0; kk < 8; kk++){
        float4 xv = *(const float4*)&v1[jr][kk*4];
        a0 += xv.x*wr[kk*4]; a1 += xv.y*wr[kk*4+1]; a2 += xv.z*wr[kk*4+2]; a3 += xv.w*wr[kk*4+3];
      }
      v2[jr][c2] = b2[c2] + (a0+a1)+(a2+a3);
    }
  }
  __syncthreads();
  {
    int o = tid;
    float wr[32];
    const float4* wp = (const float4*)(whT + o*32);
#pragma unroll
    for (int kk = 0; kk < 8; kk++) ((float4*)wr)[kk] = wp[kk];
    float bo = bh[o];
#pragma unroll 1
    for (int jr = 0; jr < 64; jr++){
      float a0=0.f,a1=0.f,a2=0.f,a3=0.f;
#pragma unroll
      for (int kk = 0; kk < 8; kk++){
        float4 xv = *(const float4*)&v2[jr][kk*4];
        a0 += xv.x*wr[kk*4]; a1 += xv.y*wr[kk*4+1]; a2 += xv.z*wr[kk*4+2]; a3 += xv.w*wr[kk*4+3];
      }
      out[(((size_t)b*64 + i)*64 + jr)*256 + o] = bo + (a0+a1)+(a2+a3);
    }
  }
}

// ---------------------------------------------------------------------------
extern "C" void kernel_launch(void* const* d_in, const int* in_sizes, int n_in,
                              void* d_out, int out_size, void* d_ws, size_t ws_size,
                              hipStream_t stream)
{
  const float* im   = (const float*)d_in[0];
  const float* ck   = (const float*)d_in[1];
  const float* cb   = (const float*)d_in[2];
  const float* ln_s = (const float*)d_in[3];
  const float* ln_b = (const float*)d_in[4];
  const float* w_is = (const float*)d_in[5];
  const float* b_is = (const float*)d_in[6];
  const float* w_ss = (const float*)d_in[7];
  const float* b_ss = (const float*)d_in[8];
  const float* w_oc = (const float*)d_in[9];
  const float* b_oc = (const float*)d_in[10];
  const float* h0   = (const float*)d_in[11];
  const float* w1   = (const float*)d_in[12];
  const float* b1   = (const float*)d_in[13];
  const float* w2   = (const float*)d_in[14];
  const float* b2   = (const float*)d_in[15];
  const float* wh   = (const float*)d_in[16];
  const float* bh   = (const float*)d_in[17];

  // Workspace layout: 133,828,608 B total (== Round-1's proven footprint).
  ushort_t* Xbuf = (ushort_t*)d_ws;        // X0 -> X1 (aliased) -> xfin
  ushort_t* xnfL = Xbuf + ACT;             // xn fragment files (per layer, overwritten)
  ushort_t* xnfR = xnfL + ACT;
  ushort_t* hnL  = xnfR + ACT;
  ushort_t* hnR  = hnL + HNE;
  ushort_t* zWp  = hnR + HNE;              // wss frags  (131072 el)
  ushort_t* wisp = zWp + 131072;           // wis frags  (131072 el)
  ushort_t* wocp = wisp + 131072;          // woc frags  (32768 el)
  float* zbias = (float*)(wocp + 32768);
  float* w1T   = zbias + 1024;
  float* w2T   = w1T + 4096;
  float* whT   = w2T + 1024;
  float* kw    = whT + 8192;

  pack_kernel<<<1220, 256, 0, stream>>>(w_is, w_ss, b_is, b_ss, w_oc, w1, w2, wh, ck,
                                        zWp, wisp, wocp, zbias, w1T, w2T, whT, kw);
  conv_kernel<<<65024, 256, 0, stream>>>(im, cb, kw, Xbuf);
  stage_kernel<<<2032, 256, 0, stream>>>(0, 0, 0, Xbuf, nullptr, nullptr,
                                         wocp, b_oc, ln_s, ln_b, xnfL, xnfR);
  diag_kernel<<<32, 512, 0, stream>>>(xnfL, xnfR, hnL, hnR, zWp, wisp, zbias, h0, 0);
  stage_kernel<<<2032, 256, 0, stream>>>(1, 0, 1, Xbuf, hnL, hnR,
                                         wocp, b_oc, ln_s, ln_b, xnfL, xnfR);
  diag_kernel<<<32, 512, 0, stream>>>(xnfL, xnfR, hnL, hnR, zWp, wisp, zbias, h0, 1);
  stage_kernel<<<2032, 256, 0, stream>>>(2, 1, 0, Xbuf, hnL, hnR,
                                         wocp, b_oc, ln_s, ln_b, xnfL, xnfR);
  head_kernel<<<1024, 256, 0, stream>>>(Xbuf, w1T, b1, w2T, b2, whT, bh, (float*)d_out);
}